// Round 2
// baseline (4713.212 us; speedup 1.0000x reference)
//
#include <hip/hip_runtime.h>
#include <hip/hip_bf16.h>
#include <stdint.h>

#define BATCH   128
#define LPAST   365
#define DIN     32
#define HHOR    8
#define NSTAT   27
#define HID     1024
#define TEMBN   256
#define TSTEPS  372      // LPAST + HHOR - 1
#define NPAST   364      // past steps (LPAST - 1)
#define INDIM   60
#define KF      64       // padded feats width

#define NGRP    8        // batch groups
#define CUPG    32       // CUs (workgroups) per group
#define BPG     16       // batches per group

#define LDS_HS  1032     // padded LDS row stride in fp16 elems (1024 + 8)

typedef _Float16 f16_t;
typedef f16_t   f16x8 __attribute__((ext_vector_type(8)));
typedef float   f32x4 __attribute__((ext_vector_type(4)));
typedef uint32_t u32x4 __attribute__((ext_vector_type(4)));

__device__ __forceinline__ f32x4 mfma16(f16x8 a, f16x8 b, f32x4 c) {
    return __builtin_amdgcn_mfma_f32_16x16x32_f16(a, b, c, 0, 0, 0);
}
__device__ __forceinline__ float sigm(float x) { return 1.f / (1.f + expf(-x)); }

// ---------------- prologue: build feats hi/lo fp16 planes [2][B][T][KF] ----
__global__ __launch_bounds__(256)
void build_feats(const float* __restrict__ xp, const float* __restrict__ nf,
                 const float* __restrict__ xf, const float* __restrict__ st,
                 f16_t* __restrict__ feats)
{
    int idx = blockIdx.x * 256 + threadIdx.x;
    if (idx >= BATCH * TSTEPS * KF) return;
    int k  = idx & (KF - 1);
    int bt = idx >> 6;
    int t  = bt % TSTEPS;
    int b  = bt / TSTEPS;
    float v = 0.f;
    if (k < DIN) {
        v = (t < LPAST) ? xp[((size_t)b * LPAST + t) * DIN + k]
                        : xf[((size_t)b * (HHOR - 1) + (t - LPAST)) * DIN + k];
    } else if (k == DIN) {
        v = (t >= NPAST) ? nf[b * HHOR + (t - NPAST)] : 0.f;
    } else if (k < DIN + 1 + NSTAT) {
        v = st[b * NSTAT + (k - DIN - 1)];
    }
    f16_t hi = (f16_t)v;
    f16_t lo = (f16_t)(v - (float)hi);
    feats[idx] = hi;
    feats[(size_t)BATCH * TSTEPS * KF + idx] = lo;
}

// ---------------- prologue: time-embedding MLP (fp32) ----------------
__global__ __launch_bounds__(256)
void time_mlp(const float* __restrict__ tv, const float* __restrict__ freqs,
              const float* __restrict__ phases,
              const float* __restrict__ W1, const float* __restrict__ b1,
              const float* __restrict__ W2, const float* __restrict__ b2,
              float* __restrict__ temb)
{
    __shared__ float emb[TEMBN];
    __shared__ float hmid[2 * TEMBN];
    int b = blockIdx.x, tid = threadIdx.x;
    float t = tv[b];
    {
        float x = t * freqs[tid] + phases[tid];
        emb[tid] = cosf(x) * 1.41421356237309515f;
    }
    __syncthreads();
    for (int j = tid; j < 2 * TEMBN; j += 256) {
        float s = b1[j];
        const float* wr = W1 + (size_t)j * TEMBN;
        for (int k = 0; k < TEMBN; k++) s += wr[k] * emb[k];
        hmid[j] = s / (1.f + expf(-s));   // SiLU
    }
    __syncthreads();
    for (int j = tid; j < HID; j += 256) {
        float s = b2[j];
        const float* wr = W2 + (size_t)j * (2 * TEMBN);
        for (int k = 0; k < 2 * TEMBN; k++) s += wr[k] * hmid[k];
        temb[(size_t)b * HID + j] = s;
    }
}

// ---------------- main persistent LSTM kernel ----------------
__global__ __launch_bounds__(256, 1)
void lstm_persist(const f16_t* __restrict__ feats,
                  const float* __restrict__ temb,
                  f16_t* hbuf, float* hfut, uint32_t* ctrs,
                  const float* __restrict__ W_ih, const float* __restrict__ W_hh,
                  const float* __restrict__ b_ih, const float* __restrict__ b_hh)
{
    // LDS: h staging (hi/lo planes, padded rows) + gate exchange.
    // Total > 80KB -> exactly 1 WG/CU (full 512-VGPR budget per lane).
    __shared__ __align__(16) f16_t hhi[16 * LDS_HS];
    __shared__ __align__(16) f16_t hlo[16 * LDS_HS];
    __shared__ __align__(16) float gbuf[128 * 20 + 2048];

    const int tid  = threadIdx.x;
    const int w    = tid >> 6;        // wave 0..3  <-> gate i,f,g,o
    const int lane = tid & 63;
    const int q    = lane >> 4;
    const int n15  = lane & 15;
    const int g    = blockIdx.x & 7;  // group (XCD-locality heuristic)
    const int m    = blockIdx.x >> 3; // member CU within group, 0..31

    // ---- load persistent weight fragments (fp16) ----
    f16x8 Bhh[2][32];                 // W_hh, single fp16 plane
    f16x8 BihH[2][2], BihL[2][2];     // W_ih, hi/lo fp16 planes
#pragma unroll
    for (int nn = 0; nn < 2; nn++) {
        const int grow = w * HID + m * 32 + nn * 16 + n15;   // global 4H row
        const float* wr = W_hh + (size_t)grow * HID;
#pragma unroll
        for (int kt = 0; kt < 32; kt++) {
            const float* s = wr + kt * 32 + q * 8;
            f16x8 f;
#pragma unroll
            for (int j = 0; j < 8; j++) f[j] = (f16_t)s[j];
            Bhh[nn][kt] = f;
        }
        const float* wr2 = W_ih + (size_t)grow * INDIM;
#pragma unroll
        for (int kt = 0; kt < 2; kt++) {
            f16x8 fh, fl;
#pragma unroll
            for (int j = 0; j < 8; j++) {
                int k = kt * 32 + q * 8 + j;
                float v = (k < INDIM) ? wr2[k] : 0.f;
                f16_t h = (f16_t)v;
                fh[j] = h;
                fl[j] = (f16_t)(v - (float)h);
            }
            BihH[nn][kt] = fh;
            BihL[nn][kt] = fl;
        }
    }

    // ---- elementwise ownership: 2 (unit,batch) pairs per thread ----
    const int p0  = tid * 2;
    const int eb  = p0 >> 5;          // batch in group, 0..15
    const int eu0 = p0 & 31;          // even local unit
    const int gb  = g * BPG + eb;     // global batch
    const int U0  = m * 32 + eu0;     // global hidden unit
    const int a0  = eu0 * 20 + eb;    // gbuf index for gate 0, pair 0
    float bias0[4], bias1[4];
#pragma unroll
    for (int gg = 0; gg < 4; gg++) {
        bias0[gg] = b_ih[gg * HID + U0]     + b_hh[gg * HID + U0];
        bias1[gg] = b_ih[gg * HID + U0 + 1] + b_hh[gg * HID + U0 + 1];
    }
    float c0 = 0.f, c1 = 0.f;

    uint32_t* ctr = ctrs + (size_t)g * 64;
    const size_t FPLANE = (size_t)BATCH * TSTEPS * KF;   // feats plane stride

#pragma unroll 1
    for (int t = 0; t < TSTEPS; t++) {
        // ---- feats A-fragments, hi+lo (global, L1/L2-cached) ----
        const f16_t* fr = feats + ((size_t)(g * BPG + n15) * TSTEPS + t) * KF + q * 8;
        u32x4 fuH0 = *(const u32x4*)(fr);
        u32x4 fuH1 = *(const u32x4*)(fr + 32);
        u32x4 fuL0 = *(const u32x4*)(fr + FPLANE);
        u32x4 fuL1 = *(const u32x4*)(fr + FPLANE + 32);

        // ---- stage h (hi/lo) from global double-buffer into padded LDS ----
        {
            const f16_t* srcH = hbuf + ((size_t)(t & 1) * 2) * (BATCH * HID)
                                     + (size_t)(g * BPG) * HID;
            const f16_t* srcL = srcH + (size_t)BATCH * HID;
#pragma unroll
            for (int i = 0; i < 8; i++) {
                int c   = tid + i * 256;        // 16B chunk id, 0..2047
                int row = c >> 7;
                int col = c & 127;
                u32x4 dh = *(const u32x4*)(srcH + c * 8);
                u32x4 dl = *(const u32x4*)(srcL + c * 8);
                *(u32x4*)(&hhi[row * LDS_HS + col * 8]) = dh;
                *(u32x4*)(&hlo[row * LDS_HS + col * 8]) = dl;
            }
        }

        // ---- input-projection MFMAs (no LDS dependency) ----
        f32x4 acc0 = {0.f, 0.f, 0.f, 0.f};
        f32x4 acc1 = {0.f, 0.f, 0.f, 0.f};
        {
            f16x8 faH0 = __builtin_bit_cast(f16x8, fuH0);
            f16x8 faH1 = __builtin_bit_cast(f16x8, fuH1);
            f16x8 faL0 = __builtin_bit_cast(f16x8, fuL0);
            f16x8 faL1 = __builtin_bit_cast(f16x8, fuL1);
            acc0 = mfma16(faH0, BihH[0][0], acc0);
            acc0 = mfma16(faH1, BihH[0][1], acc0);
            acc0 = mfma16(faH0, BihL[0][0], acc0);
            acc0 = mfma16(faH1, BihL[0][1], acc0);
            acc0 = mfma16(faL0, BihH[0][0], acc0);
            acc0 = mfma16(faL1, BihH[0][1], acc0);
            acc1 = mfma16(faH0, BihH[1][0], acc1);
            acc1 = mfma16(faH1, BihH[1][1], acc1);
            acc1 = mfma16(faH0, BihL[1][0], acc1);
            acc1 = mfma16(faH1, BihL[1][1], acc1);
            acc1 = mfma16(faL0, BihH[1][0], acc1);
            acc1 = mfma16(faL1, BihH[1][1], acc1);
        }
        __syncthreads();   // staging visible

        // ---- recurrent MFMAs: gates += W_hh * (h_hi + h_lo) ----
#pragma unroll
        for (int kt = 0; kt < 32; kt++) {
            u32x4 uh = *(const u32x4*)(&hhi[n15 * LDS_HS + kt * 32 + q * 8]);
            u32x4 ul = *(const u32x4*)(&hlo[n15 * LDS_HS + kt * 32 + q * 8]);
            f16x8 ah = __builtin_bit_cast(f16x8, uh);
            f16x8 al = __builtin_bit_cast(f16x8, ul);
            acc0 = mfma16(ah, Bhh[0][kt], acc0);
            acc1 = mfma16(ah, Bhh[1][kt], acc1);
            acc0 = mfma16(al, Bhh[0][kt], acc0);
            acc1 = mfma16(al, Bhh[1][kt], acc1);
        }

        // ---- exchange gates through LDS ----
        {
            int lr0 = w * 32 + n15;        // nn=0 rows
            *(f32x4*)(&gbuf[lr0 * 20 + q * 4])        = acc0;
            *(f32x4*)(&gbuf[(lr0 + 16) * 20 + q * 4]) = acc1;
        }
        __syncthreads();

        // ---- elementwise LSTM cell (fp32), 2 pairs per thread ----
        float xi0 = gbuf[a0]        + bias0[0];
        float xf0 = gbuf[a0 + 640]  + bias0[1];
        float xg0 = gbuf[a0 + 1280] + bias0[2];
        float xo0 = gbuf[a0 + 1920] + bias0[3];
        c0 = sigm(xf0) * c0 + sigm(xi0) * tanhf(xg0);
        float h0v = sigm(xo0) * tanhf(c0);

        float xi1 = gbuf[a0 + 20]        + bias1[0];
        float xf1 = gbuf[a0 + 20 + 640]  + bias1[1];
        float xg1 = gbuf[a0 + 20 + 1280] + bias1[2];
        float xo1 = gbuf[a0 + 20 + 1920] + bias1[3];
        c1 = sigm(xf1) * c1 + sigm(xi1) * tanhf(xg1);
        float h1v = sigm(xo1) * tanhf(c1);

        if (t == NPAST - 1) {   // boundary: h0 = h_p + temb, c0 = c_p + temb
            float t0 = temb[(size_t)gb * HID + U0];
            float t1 = temb[(size_t)gb * HID + U0 + 1];
            h0v += t0; c0 += t0;
            h1v += t1; c1 += t1;
        }
        if (t >= NPAST) {       // future pass: store fp32 h for head
            float* hf = hfut + ((size_t)(t - NPAST) * BATCH + gb) * HID;
            hf[U0]     = h0v;
            hf[U0 + 1] = h1v;
        }

        // ---- broadcast new h (hi/lo fp16) to other buffer ----
        {
            f16_t h0h = (f16_t)h0v; f16_t h0l = (f16_t)(h0v - (float)h0h);
            f16_t h1h = (f16_t)h1v; f16_t h1l = (f16_t)(h1v - (float)h1h);
            uint32_t ph = (uint32_t)__builtin_bit_cast(uint16_t, h0h)
                        | ((uint32_t)__builtin_bit_cast(uint16_t, h1h) << 16);
            uint32_t pl = (uint32_t)__builtin_bit_cast(uint16_t, h0l)
                        | ((uint32_t)__builtin_bit_cast(uint16_t, h1l) << 16);
            size_t ob = ((size_t)((t + 1) & 1) * 2) * (BATCH * HID)
                      + (size_t)gb * HID + U0;
            *(uint32_t*)(hbuf + ob)                       = ph;
            *(uint32_t*)(hbuf + ob + (size_t)BATCH * HID) = pl;
        }

        // ---- per-group device barrier ----
        __syncthreads();   // drain all threads' global stores (vmcnt at barrier)
        if (tid == 0) {
            __hip_atomic_fetch_add(ctr, 1u, __ATOMIC_RELEASE, __HIP_MEMORY_SCOPE_AGENT);
            uint32_t tgt = (uint32_t)CUPG * (uint32_t)(t + 1);
            while (__hip_atomic_load(ctr, __ATOMIC_RELAXED, __HIP_MEMORY_SCOPE_AGENT) < tgt)
                __builtin_amdgcn_s_sleep(1);
            __builtin_amdgcn_fence(__ATOMIC_ACQUIRE, "agent");  // before releasing WG
        }
        __syncthreads();
    }
}

// ---------------- epilogue: head out[b,s] = h . Wh + bh ----------------
__global__ __launch_bounds__(256)
void head(const float* __restrict__ hfut, const float* __restrict__ Wh,
          const float* __restrict__ bh, float* __restrict__ out)
{
    int b = blockIdx.x >> 3, s = blockIdx.x & 7;
    int tid = threadIdx.x;
    const float* h = hfut + ((size_t)s * BATCH + b) * HID;
    float4 hv = *(const float4*)(h + tid * 4);
    float4 wv = *(const float4*)(Wh + tid * 4);
    float p = hv.x * wv.x + hv.y * wv.y + hv.z * wv.z + hv.w * wv.w;
#pragma unroll
    for (int off = 32; off > 0; off >>= 1) p += __shfl_down(p, off);
    __shared__ float r[4];
    if ((tid & 63) == 0) r[tid >> 6] = p;
    __syncthreads();
    if (tid == 0) out[b * HHOR + s] = r[0] + r[1] + r[2] + r[3] + bh[0];
}

extern "C" void kernel_launch(void* const* d_in, const int* in_sizes, int n_in,
                              void* d_out, int out_size, void* d_ws, size_t ws_size,
                              hipStream_t stream)
{
    const float* x_past = (const float*)d_in[0];
    const float* noisy  = (const float*)d_in[1];
    const float* tv     = (const float*)d_in[2];
    const float* x_fut  = (const float*)d_in[3];
    const float* statc  = (const float*)d_in[4];
    const float* W_ih   = (const float*)d_in[5];
    const float* W_hh   = (const float*)d_in[6];
    const float* b_ih   = (const float*)d_in[7];
    const float* b_hh   = (const float*)d_in[8];
    const float* freqs  = (const float*)d_in[9];
    const float* phases = (const float*)d_in[10];
    const float* W1     = (const float*)d_in[11];
    const float* b1     = (const float*)d_in[12];
    const float* W2     = (const float*)d_in[13];
    const float* b2     = (const float*)d_in[14];
    const float* Wh     = (const float*)d_in[15];
    const float* bh     = (const float*)d_in[16];
    float* out = (float*)d_out;

    char* ws = (char*)d_ws;
    const size_t sz_feats = (size_t)2 * BATCH * TSTEPS * KF * 2;   // 2 planes
    const size_t off_temb = sz_feats;
    const size_t sz_temb  = (size_t)BATCH * HID * 4;
    const size_t off_hbuf = off_temb + sz_temb;
    const size_t sz_hbuf  = (size_t)2 * 2 * BATCH * HID * 2;       // 2 bufs x 2 planes
    const size_t off_hfut = off_hbuf + sz_hbuf;
    const size_t sz_hfut  = (size_t)HHOR * BATCH * HID * 4;
    const size_t off_ctr  = off_hfut + sz_hfut;

    f16_t*    feats = (f16_t*)(ws);
    float*    temb  = (float*)(ws + off_temb);
    f16_t*    hbuf  = (f16_t*)(ws + off_hbuf);
    float*    hfut  = (float*)(ws + off_hfut);
    uint32_t* ctrs  = (uint32_t*)(ws + off_ctr);

    // zero h double-buffer slot 0 (h_0 = 0) and the group barrier counters
    hipMemsetAsync(hbuf, 0, (size_t)2 * BATCH * HID * 2, stream);
    hipMemsetAsync(ctrs, 0, (size_t)NGRP * 64 * sizeof(uint32_t), stream);

    build_feats<<<(BATCH * TSTEPS * KF) / 256, 256, 0, stream>>>(x_past, noisy, x_fut, statc, feats);
    time_mlp<<<BATCH, 256, 0, stream>>>(tv, freqs, phases, W1, b1, W2, b2, temb);
    lstm_persist<<<NGRP * CUPG, 256, 0, stream>>>(feats, temb, hbuf, hfut, ctrs,
                                                  W_ih, W_hh, b_ih, b_hh);
    head<<<BATCH * HHOR, 256, 0, stream>>>(hfut, Wh, bh, out);
}

// Round 3
// 2118.947 us; speedup vs baseline: 2.2243x; 2.2243x over previous
//
#include <hip/hip_runtime.h>
#include <hip/hip_bf16.h>
#include <stdint.h>

#define BATCH   128
#define LPAST   365
#define DIN     32
#define HHOR    8
#define NSTAT   27
#define HID     1024
#define TEMBN   256
#define TSTEPS  372      // LPAST + HHOR - 1
#define NPAST   364      // past steps (LPAST - 1)
#define INDIM   60
#define KF      64       // padded feats width

#define NGRP    8        // batch groups
#define CUPG    32       // CUs (workgroups) per group
#define BPG     16       // batches per group

#define LDS_HS  1032     // padded LDS row stride in fp16 elems (1024 + 8)

typedef _Float16 f16_t;
typedef f16_t   f16x8 __attribute__((ext_vector_type(8)));
typedef float   f32x4 __attribute__((ext_vector_type(4)));
typedef uint32_t u32x4 __attribute__((ext_vector_type(4)));

__device__ __forceinline__ f32x4 mfma16(f16x8 a, f16x8 b, f32x4 c) {
    return __builtin_amdgcn_mfma_f32_16x16x32_f16(a, b, c, 0, 0, 0);
}
__device__ __forceinline__ float sigm(float x) { return 1.f / (1.f + expf(-x)); }

// ---------------- prologue: build feats hi/lo fp16 planes [2][B][T][KF] ----
__global__ __launch_bounds__(256)
void build_feats(const float* __restrict__ xp, const float* __restrict__ nf,
                 const float* __restrict__ xf, const float* __restrict__ st,
                 f16_t* __restrict__ feats)
{
    int idx = blockIdx.x * 256 + threadIdx.x;
    if (idx >= BATCH * TSTEPS * KF) return;
    int k  = idx & (KF - 1);
    int bt = idx >> 6;
    int t  = bt % TSTEPS;
    int b  = bt / TSTEPS;
    float v = 0.f;
    if (k < DIN) {
        v = (t < LPAST) ? xp[((size_t)b * LPAST + t) * DIN + k]
                        : xf[((size_t)b * (HHOR - 1) + (t - LPAST)) * DIN + k];
    } else if (k == DIN) {
        v = (t >= NPAST) ? nf[b * HHOR + (t - NPAST)] : 0.f;
    } else if (k < DIN + 1 + NSTAT) {
        v = st[b * NSTAT + (k - DIN - 1)];
    }
    f16_t hi = (f16_t)v;
    f16_t lo = (f16_t)(v - (float)hi);
    feats[idx] = hi;
    feats[(size_t)BATCH * TSTEPS * KF + idx] = lo;
}

// ---------------- prologue: time-embedding MLP (fp32) ----------------
__global__ __launch_bounds__(256)
void time_mlp(const float* __restrict__ tv, const float* __restrict__ freqs,
              const float* __restrict__ phases,
              const float* __restrict__ W1, const float* __restrict__ b1,
              const float* __restrict__ W2, const float* __restrict__ b2,
              float* __restrict__ temb)
{
    __shared__ float emb[TEMBN];
    __shared__ float hmid[2 * TEMBN];
    int b = blockIdx.x, tid = threadIdx.x;
    float t = tv[b];
    {
        float x = t * freqs[tid] + phases[tid];
        emb[tid] = cosf(x) * 1.41421356237309515f;
    }
    __syncthreads();
    for (int j = tid; j < 2 * TEMBN; j += 256) {
        float s = b1[j];
        const float* wr = W1 + (size_t)j * TEMBN;
        for (int k = 0; k < TEMBN; k++) s += wr[k] * emb[k];
        hmid[j] = s / (1.f + expf(-s));   // SiLU
    }
    __syncthreads();
    for (int j = tid; j < HID; j += 256) {
        float s = b2[j];
        const float* wr = W2 + (size_t)j * (2 * TEMBN);
        for (int k = 0; k < 2 * TEMBN; k++) s += wr[k] * hmid[k];
        temb[(size_t)b * HID + j] = s;
    }
}

// ---------------- main persistent LSTM kernel ----------------
__global__ __launch_bounds__(256, 1)
void lstm_persist(const f16_t* __restrict__ feats,
                  const float* __restrict__ temb,
                  f16_t* hbuf, float* hfut, uint32_t* flags,
                  const float* __restrict__ W_ih, const float* __restrict__ W_hh,
                  const float* __restrict__ b_ih, const float* __restrict__ b_hh)
{
    // LDS: h staging (hi/lo planes, padded rows) + gate exchange.
    // Total > 80KB -> exactly 1 WG/CU (full 512-VGPR budget per lane).
    __shared__ __align__(16) f16_t hhi[16 * LDS_HS];
    __shared__ __align__(16) f16_t hlo[16 * LDS_HS];
    __shared__ __align__(16) float gbuf[128 * 20 + 2048];

    const int tid  = threadIdx.x;
    const int w    = tid >> 6;        // wave 0..3  <-> gate i,f,g,o
    const int lane = tid & 63;
    const int q    = lane >> 4;
    const int n15  = lane & 15;
    const int g    = blockIdx.x & 7;  // group (XCD-locality heuristic)
    const int m    = blockIdx.x >> 3; // member CU within group, 0..31

    // ---- load persistent weight fragments (fp16) ----
    f16x8 Bhh[2][32];                 // W_hh, single fp16 plane
    f16x8 BihH[2][2], BihL[2][2];     // W_ih, hi/lo fp16 planes
#pragma unroll
    for (int nn = 0; nn < 2; nn++) {
        const int grow = w * HID + m * 32 + nn * 16 + n15;   // global 4H row
        const float* wr = W_hh + (size_t)grow * HID;
#pragma unroll
        for (int kt = 0; kt < 32; kt++) {
            const float* s = wr + kt * 32 + q * 8;
            f16x8 f;
#pragma unroll
            for (int j = 0; j < 8; j++) f[j] = (f16_t)s[j];
            Bhh[nn][kt] = f;
        }
        const float* wr2 = W_ih + (size_t)grow * INDIM;
#pragma unroll
        for (int kt = 0; kt < 2; kt++) {
            f16x8 fh, fl;
#pragma unroll
            for (int j = 0; j < 8; j++) {
                int k = kt * 32 + q * 8 + j;
                float v = (k < INDIM) ? wr2[k] : 0.f;
                f16_t h = (f16_t)v;
                fh[j] = h;
                fl[j] = (f16_t)(v - (float)h);
            }
            BihH[nn][kt] = fh;
            BihL[nn][kt] = fl;
        }
    }

    // ---- elementwise ownership: 2 (unit,batch) pairs per thread ----
    const int p0  = tid * 2;
    const int eb  = p0 >> 5;          // batch in group, 0..15
    const int eu0 = p0 & 31;          // even local unit
    const int gb  = g * BPG + eb;     // global batch
    const int U0  = m * 32 + eu0;     // global hidden unit
    const int a0  = eu0 * 20 + eb;    // gbuf index for gate 0, pair 0
    float bias0[4], bias1[4];
#pragma unroll
    for (int gg = 0; gg < 4; gg++) {
        bias0[gg] = b_ih[gg * HID + U0]     + b_hh[gg * HID + U0];
        bias1[gg] = b_ih[gg * HID + U0 + 1] + b_hh[gg * HID + U0 + 1];
    }
    float c0 = 0.f, c1 = 0.f;

    uint32_t* gflags = flags + (size_t)g * CUPG;
    const size_t FPLANE = (size_t)BATCH * TSTEPS * KF;   // feats plane stride

#pragma unroll 1
    for (int t = 0; t < TSTEPS; t++) {
        // ---- feats A-fragments, hi+lo (plain loads; feats is read-only) ----
        const f16_t* fr = feats + ((size_t)(g * BPG + n15) * TSTEPS + t) * KF + q * 8;
        u32x4 fuH0 = *(const u32x4*)(fr);
        u32x4 fuH1 = *(const u32x4*)(fr + 32);
        u32x4 fuL0 = *(const u32x4*)(fr + FPLANE);
        u32x4 fuL1 = *(const u32x4*)(fr + FPLANE + 32);

        // ---- stage h (hi/lo) from MALL-coherent double-buffer via sc1 loads ----
        {
            const f16_t* srcH = hbuf + ((size_t)(t & 1) * 2) * (BATCH * HID)
                                     + (size_t)(g * BPG) * HID;
            const f16_t* srcL = srcH + (size_t)BATCH * HID;
            // chunk i (i=0..7): byte offset tid*16 + i*4096. Bias base +2048 so
            // chunk pair (2k,2k+1) = base_k + {-2048,+2048} imm offsets.
            const char* bH = (const char*)srcH + tid * 16 + 2048;
            const char* bL = (const char*)srcL + tid * 16 + 2048;
            const char* aH0 = bH;            const char* aL0 = bL;
            const char* aH1 = bH + 8192;     const char* aL1 = bL + 8192;
            const char* aH2 = bH + 16384;    const char* aL2 = bL + 16384;
            const char* aH3 = bH + 24576;    const char* aL3 = bL + 24576;
            u32x4 dh0, dh1, dh2, dh3, dh4, dh5, dh6, dh7;
            u32x4 dl0, dl1, dl2, dl3, dl4, dl5, dl6, dl7;
            asm volatile(
                "global_load_dwordx4 %0,  %16, off offset:-2048 sc1\n\t"
                "global_load_dwordx4 %1,  %16, off offset:2048  sc1\n\t"
                "global_load_dwordx4 %2,  %17, off offset:-2048 sc1\n\t"
                "global_load_dwordx4 %3,  %17, off offset:2048  sc1\n\t"
                "global_load_dwordx4 %4,  %18, off offset:-2048 sc1\n\t"
                "global_load_dwordx4 %5,  %18, off offset:2048  sc1\n\t"
                "global_load_dwordx4 %6,  %19, off offset:-2048 sc1\n\t"
                "global_load_dwordx4 %7,  %19, off offset:2048  sc1\n\t"
                "global_load_dwordx4 %8,  %20, off offset:-2048 sc1\n\t"
                "global_load_dwordx4 %9,  %20, off offset:2048  sc1\n\t"
                "global_load_dwordx4 %10, %21, off offset:-2048 sc1\n\t"
                "global_load_dwordx4 %11, %21, off offset:2048  sc1\n\t"
                "global_load_dwordx4 %12, %22, off offset:-2048 sc1\n\t"
                "global_load_dwordx4 %13, %22, off offset:2048  sc1\n\t"
                "global_load_dwordx4 %14, %23, off offset:-2048 sc1\n\t"
                "global_load_dwordx4 %15, %23, off offset:2048  sc1\n\t"
                "s_waitcnt vmcnt(0)"
                : "=&v"(dh0), "=&v"(dh1), "=&v"(dh2), "=&v"(dh3),
                  "=&v"(dh4), "=&v"(dh5), "=&v"(dh6), "=&v"(dh7),
                  "=&v"(dl0), "=&v"(dl1), "=&v"(dl2), "=&v"(dl3),
                  "=&v"(dl4), "=&v"(dl5), "=&v"(dl6), "=&v"(dl7)
                : "v"(aH0), "v"(aH1), "v"(aH2), "v"(aH3),
                  "v"(aL0), "v"(aL1), "v"(aL2), "v"(aL3)
                : "memory");
            u32x4 DH[8] = {dh0, dh1, dh2, dh3, dh4, dh5, dh6, dh7};
            u32x4 DL[8] = {dl0, dl1, dl2, dl3, dl4, dl5, dl6, dl7};
#pragma unroll
            for (int i = 0; i < 8; i++) {
                int c   = tid + i * 256;        // 16B chunk id, 0..2047
                int row = c >> 7;
                int col = c & 127;
                *(u32x4*)(&hhi[row * LDS_HS + col * 8]) = DH[i];
                *(u32x4*)(&hlo[row * LDS_HS + col * 8]) = DL[i];
            }
        }

        // ---- input-projection MFMAs (no LDS dependency) ----
        f32x4 acc0 = {0.f, 0.f, 0.f, 0.f};
        f32x4 acc1 = {0.f, 0.f, 0.f, 0.f};
        {
            f16x8 faH0 = __builtin_bit_cast(f16x8, fuH0);
            f16x8 faH1 = __builtin_bit_cast(f16x8, fuH1);
            f16x8 faL0 = __builtin_bit_cast(f16x8, fuL0);
            f16x8 faL1 = __builtin_bit_cast(f16x8, fuL1);
            acc0 = mfma16(faH0, BihH[0][0], acc0);
            acc0 = mfma16(faH1, BihH[0][1], acc0);
            acc0 = mfma16(faH0, BihL[0][0], acc0);
            acc0 = mfma16(faH1, BihL[0][1], acc0);
            acc0 = mfma16(faL0, BihH[0][0], acc0);
            acc0 = mfma16(faL1, BihH[0][1], acc0);
            acc1 = mfma16(faH0, BihH[1][0], acc1);
            acc1 = mfma16(faH1, BihH[1][1], acc1);
            acc1 = mfma16(faH0, BihL[1][0], acc1);
            acc1 = mfma16(faH1, BihL[1][1], acc1);
            acc1 = mfma16(faL0, BihH[1][0], acc1);
            acc1 = mfma16(faL1, BihH[1][1], acc1);
        }
        __syncthreads();   // staging visible

        // ---- recurrent MFMAs: gates += W_hh * (h_hi + h_lo) ----
#pragma unroll
        for (int kt = 0; kt < 32; kt++) {
            u32x4 uh = *(const u32x4*)(&hhi[n15 * LDS_HS + kt * 32 + q * 8]);
            u32x4 ul = *(const u32x4*)(&hlo[n15 * LDS_HS + kt * 32 + q * 8]);
            f16x8 ah = __builtin_bit_cast(f16x8, uh);
            f16x8 al = __builtin_bit_cast(f16x8, ul);
            acc0 = mfma16(ah, Bhh[0][kt], acc0);
            acc1 = mfma16(ah, Bhh[1][kt], acc1);
            acc0 = mfma16(al, Bhh[0][kt], acc0);
            acc1 = mfma16(al, Bhh[1][kt], acc1);
        }

        // ---- exchange gates through LDS ----
        {
            int lr0 = w * 32 + n15;        // nn=0 rows
            *(f32x4*)(&gbuf[lr0 * 20 + q * 4])        = acc0;
            *(f32x4*)(&gbuf[(lr0 + 16) * 20 + q * 4]) = acc1;
        }
        __syncthreads();

        // ---- elementwise LSTM cell (fp32), 2 pairs per thread ----
        float xi0 = gbuf[a0]        + bias0[0];
        float xf0 = gbuf[a0 + 640]  + bias0[1];
        float xg0 = gbuf[a0 + 1280] + bias0[2];
        float xo0 = gbuf[a0 + 1920] + bias0[3];
        c0 = sigm(xf0) * c0 + sigm(xi0) * tanhf(xg0);
        float h0v = sigm(xo0) * tanhf(c0);

        float xi1 = gbuf[a0 + 20]        + bias1[0];
        float xf1 = gbuf[a0 + 20 + 640]  + bias1[1];
        float xg1 = gbuf[a0 + 20 + 1280] + bias1[2];
        float xo1 = gbuf[a0 + 20 + 1920] + bias1[3];
        c1 = sigm(xf1) * c1 + sigm(xi1) * tanhf(xg1);
        float h1v = sigm(xo1) * tanhf(c1);

        if (t == NPAST - 1) {   // boundary: h0 = h_p + temb, c0 = c_p + temb
            float t0 = temb[(size_t)gb * HID + U0];
            float t1 = temb[(size_t)gb * HID + U0 + 1];
            h0v += t0; c0 += t0;
            h1v += t1; c1 += t1;
        }
        if (t >= NPAST) {       // future pass: store fp32 h for head
            float* hf = hfut + ((size_t)(t - NPAST) * BATCH + gb) * HID;
            hf[U0]     = h0v;
            hf[U0 + 1] = h1v;
        }

        // ---- broadcast new h (hi/lo fp16) via sc1 (MALL-coherent) stores ----
        {
            f16_t h0h = (f16_t)h0v; f16_t h0l = (f16_t)(h0v - (float)h0h);
            f16_t h1h = (f16_t)h1v; f16_t h1l = (f16_t)(h1v - (float)h1h);
            uint32_t ph = (uint32_t)__builtin_bit_cast(uint16_t, h0h)
                        | ((uint32_t)__builtin_bit_cast(uint16_t, h1h) << 16);
            uint32_t pl = (uint32_t)__builtin_bit_cast(uint16_t, h0l)
                        | ((uint32_t)__builtin_bit_cast(uint16_t, h1l) << 16);
            size_t ob = ((size_t)((t + 1) & 1) * 2) * (BATCH * HID)
                      + (size_t)gb * HID + U0;
            __hip_atomic_store((uint32_t*)(hbuf + ob), ph,
                               __ATOMIC_RELAXED, __HIP_MEMORY_SCOPE_AGENT);
            __hip_atomic_store((uint32_t*)(hbuf + ob + (size_t)BATCH * HID), pl,
                               __ATOMIC_RELAXED, __HIP_MEMORY_SCOPE_AGENT);
        }

        // ---- per-group flag barrier (no fences, no L2 maintenance) ----
        __syncthreads();   // s_waitcnt vmcnt(0): all sc1 stores retired at MALL
        if (tid == 0)      // publish: this CU finished step t+1's h
            __hip_atomic_store(&gflags[m], (uint32_t)(t + 1),
                               __ATOMIC_RELAXED, __HIP_MEMORY_SCOPE_AGENT);
        if (tid < 64) {    // wave 0 polls all 32 member flags
            uint32_t tgt = (uint32_t)(t + 1);
            for (;;) {
                uint32_t v = tgt;
                if (lane < CUPG)
                    v = __hip_atomic_load(&gflags[lane],
                                          __ATOMIC_RELAXED, __HIP_MEMORY_SCOPE_AGENT);
                if (__all(v >= tgt)) break;
            }
        }
        __syncthreads();
    }
}

// ---------------- epilogue: head out[b,s] = h . Wh + bh ----------------
__global__ __launch_bounds__(256)
void head(const float* __restrict__ hfut, const float* __restrict__ Wh,
          const float* __restrict__ bh, float* __restrict__ out)
{
    int b = blockIdx.x >> 3, s = blockIdx.x & 7;
    int tid = threadIdx.x;
    const float* h = hfut + ((size_t)s * BATCH + b) * HID;
    float4 hv = *(const float4*)(h + tid * 4);
    float4 wv = *(const float4*)(Wh + tid * 4);
    float p = hv.x * wv.x + hv.y * wv.y + hv.z * wv.z + hv.w * wv.w;
#pragma unroll
    for (int off = 32; off > 0; off >>= 1) p += __shfl_down(p, off);
    __shared__ float r[4];
    if ((tid & 63) == 0) r[tid >> 6] = p;
    __syncthreads();
    if (tid == 0) out[b * HHOR + s] = r[0] + r[1] + r[2] + r[3] + bh[0];
}

extern "C" void kernel_launch(void* const* d_in, const int* in_sizes, int n_in,
                              void* d_out, int out_size, void* d_ws, size_t ws_size,
                              hipStream_t stream)
{
    const float* x_past = (const float*)d_in[0];
    const float* noisy  = (const float*)d_in[1];
    const float* tv     = (const float*)d_in[2];
    const float* x_fut  = (const float*)d_in[3];
    const float* statc  = (const float*)d_in[4];
    const float* W_ih   = (const float*)d_in[5];
    const float* W_hh   = (const float*)d_in[6];
    const float* b_ih   = (const float*)d_in[7];
    const float* b_hh   = (const float*)d_in[8];
    const float* freqs  = (const float*)d_in[9];
    const float* phases = (const float*)d_in[10];
    const float* W1     = (const float*)d_in[11];
    const float* b1     = (const float*)d_in[12];
    const float* W2     = (const float*)d_in[13];
    const float* b2     = (const float*)d_in[14];
    const float* Wh     = (const float*)d_in[15];
    const float* bh     = (const float*)d_in[16];
    float* out = (float*)d_out;

    char* ws = (char*)d_ws;
    const size_t sz_feats = (size_t)2 * BATCH * TSTEPS * KF * 2;   // 2 planes
    const size_t off_temb = sz_feats;
    const size_t sz_temb  = (size_t)BATCH * HID * 4;
    const size_t off_hbuf = off_temb + sz_temb;
    const size_t sz_hbuf  = (size_t)2 * 2 * BATCH * HID * 2;       // 2 bufs x 2 planes
    const size_t off_hfut = off_hbuf + sz_hbuf;
    const size_t sz_hfut  = (size_t)HHOR * BATCH * HID * 4;
    const size_t off_flag = off_hfut + sz_hfut;

    f16_t*    feats = (f16_t*)(ws);
    float*    temb  = (float*)(ws + off_temb);
    f16_t*    hbuf  = (f16_t*)(ws + off_hbuf);
    float*    hfut  = (float*)(ws + off_hfut);
    uint32_t* flags = (uint32_t*)(ws + off_flag);

    // zero h double-buffer slot 0 (h_0 = 0) and the per-CU flags
    hipMemsetAsync(hbuf, 0, (size_t)2 * BATCH * HID * 2, stream);
    hipMemsetAsync(flags, 0, (size_t)NGRP * CUPG * sizeof(uint32_t), stream);

    build_feats<<<(BATCH * TSTEPS * KF) / 256, 256, 0, stream>>>(x_past, noisy, x_fut, statc, feats);
    time_mlp<<<BATCH, 256, 0, stream>>>(tv, freqs, phases, W1, b1, W2, b2, temb);
    lstm_persist<<<NGRP * CUPG, 256, 0, stream>>>(feats, temb, hbuf, hfut, flags,
                                                  W_ih, W_hh, b_ih, b_hh);
    head<<<BATCH * HHOR, 256, 0, stream>>>(hfut, Wh, bh, out);
}